// Round 3
// baseline (482.270 us; speedup 1.0000x reference)
//
#include <hip/hip_runtime.h>

#define NB 2048
#define NULL_ATT (-4194304.0f)

typedef __attribute__((ext_vector_type(8))) short bf16x8;
typedef __attribute__((ext_vector_type(4))) float f32x4;

// Precomputed once per launch (module-scope device memory; no hipMalloc).
__device__ __align__(16) short g_wh[256 * 256];  // bf16 hi of W1[:,256:512]
__device__ __align__(16) short g_wl[256 * 256];  // bf16 lo residual
__device__ float g_iq[NB * 256];                 // item part of query + b1

// swizzled element offset into a [32][256] short LDS array.
// 16B granules; XOR with (s&7) spreads A-frag reads across banks (2-way = free).
__device__ __forceinline__ int qoff(int s, int k) {
    int g = k >> 3;
    return s * 256 + (((g ^ (s & 7)) << 3) | (k & 7));
}

__device__ __forceinline__ void splitf(float f, short& hi, short& lo) {
    unsigned u = __builtin_bit_cast(unsigned, f);
    float fh = __builtin_bit_cast(float, u & 0xFFFF0000u);
    hi = (short)(u >> 16);
    lo = (short)(__builtin_bit_cast(unsigned, f - fh) >> 16);  // exact residual
}

__device__ __forceinline__ void cvt8r(float4 a, float4 b, bf16x8& hi, bf16x8& lo) {
    float f[8] = {a.x, a.y, a.z, a.w, b.x, b.y, b.z, b.w};
    #pragma unroll
    for (int j = 0; j < 8; ++j) { short h, l; splitf(f[j], h, l); hi[j] = h; lo[j] = l; }
}

__device__ __forceinline__ f32x4 mac3(bf16x8 ah, bf16x8 al, bf16x8 bh, bf16x8 bl, f32x4 c) {
    c = __builtin_amdgcn_mfma_f32_16x16x32_bf16(ah, bh, c, 0, 0, 0);
    c = __builtin_amdgcn_mfma_f32_16x16x32_bf16(ah, bl, c, 0, 0, 0);
    c = __builtin_amdgcn_mfma_f32_16x16x32_bf16(al, bh, c, 0, 0, 0);
    return c;
}

__global__ void split_w1(const float* __restrict__ W1) {
    int j = blockIdx.x, k = threadIdx.x;
    short h, l;
    splitf(W1[(size_t)j * 512 + 256 + k], h, l);
    g_wh[j * 256 + k] = h;
    g_wl[j * 256 + k] = l;
}

__global__ void calc_iq(const float* __restrict__ item_emb,
                        const float* __restrict__ W1,
                        const float* __restrict__ b1) {
    int b = blockIdx.x, t = threadIdx.x;
    const float* irow = item_emb + (size_t)b * 256;  // uniform -> s_load
    const float* wrow = W1 + (size_t)t * 512;
    float acc = b1[t];
    #pragma unroll 8
    for (int k = 0; k < 256; k += 4) {
        float4 w4 = *(const float4*)(wrow + k);
        float4 i4 = *(const float4*)(irow + k);
        acc += w4.x * i4.x + w4.y * i4.y + w4.z * i4.z + w4.w * i4.w;
    }
    g_iq[(size_t)b * 256 + t] = acc;
}

__global__ __launch_bounds__(256, 4) void coatt_fused(
    const float* __restrict__ x_session,   // [B,64,256]
    const int*   __restrict__ session_len, // [B]
    const float* __restrict__ user_hist,   // [B,256,256]
    const int*   __restrict__ hist_len,    // [B]
    float* __restrict__ out)               // [B*256 rep | B*256 score]
{
    const int b = blockIdx.x;
    const int t = threadIdx.x;
    const int wave = t >> 6;
    const int lane = t & 63;
    const int lr  = lane & 15;
    const int lo8 = lane >> 4;
    const int sl = session_len[b];
    const int hl = hist_len[b];

    __shared__ __align__(16) short qh[32 * 256];   // 16 KB
    __shared__ __align__(16) short ql[32 * 256];   // 16 KB
    __shared__ float sMax[256];
    __shared__ float wts[256];
    __shared__ float red[8];

    sMax[t] = NULL_ATT;

    const int hb = wave * 64;
    const int jb = wave * 64;
    const int nht = (hl > hb) ? min(4, (hl - hb + 15) >> 4) : 0;
    const float* hrow = user_hist + (size_t)b * 256 * 256;
    float mrun[4] = {NULL_ATT, NULL_ATT, NULL_ATT, NULL_ATT};

    const int nsh = (hl > 0) ? ((sl + 31) >> 5) : 0;   // s-halves to process (uniform)

    for (int sh = 0; sh < nsh; ++sh) {
        const int s0 = sh * 32;
        const int nstH = min(2, (sl - s0 + 15) >> 4);  // 1 or 2, uniform

        // ---- Phase 1 (MFMA): q[s0+s][j] = iq[j] + x[s][:] @ W1x[j][:] ----
        {
            f32x4 acc1[2][4];
            #pragma unroll
            for (int jt = 0; jt < 4; ++jt) {
                float v = g_iq[(size_t)b * 256 + jb + jt * 16 + lr];
                f32x4 iv = {v, v, v, v};
                acc1[0][jt] = iv; acc1[1][jt] = iv;
            }
            const float* xb = x_session + ((size_t)b * 64 + s0) * 256;
            float4 xr[2][2];
            {
                const float* p = xb + (size_t)lr * 256 + lo8 * 8;
                xr[0][0] = *(const float4*)p; xr[0][1] = *(const float4*)(p + 4);
                if (nstH > 1) {
                    const float* q2 = p + 16 * 256;
                    xr[1][0] = *(const float4*)q2; xr[1][1] = *(const float4*)(q2 + 4);
                }
            }
            for (int kc = 0; kc < 8; ++kc) {
                bf16x8 ah[2], al[2];
                cvt8r(xr[0][0], xr[0][1], ah[0], al[0]);
                if (nstH > 1) cvt8r(xr[1][0], xr[1][1], ah[1], al[1]);
                if (kc < 7) {   // prefetch next kc
                    const float* p = xb + (size_t)lr * 256 + (kc + 1) * 32 + lo8 * 8;
                    xr[0][0] = *(const float4*)p; xr[0][1] = *(const float4*)(p + 4);
                    if (nstH > 1) {
                        const float* q2 = p + 16 * 256;
                        xr[1][0] = *(const float4*)q2; xr[1][1] = *(const float4*)(q2 + 4);
                    }
                }
                #pragma unroll
                for (int jt = 0; jt < 4; ++jt) {
                    int off = (jb + jt * 16 + lr) * 256 + kc * 32 + lo8 * 8;
                    bf16x8 bh = *(const bf16x8*)&g_wh[off];
                    bf16x8 bl = *(const bf16x8*)&g_wl[off];
                    acc1[0][jt] = mac3(ah[0], al[0], bh, bl, acc1[0][jt]);
                    if (nstH > 1) acc1[1][jt] = mac3(ah[1], al[1], bh, bl, acc1[1][jt]);
                }
            }
            #pragma unroll
            for (int st = 0; st < 2; ++st) if (st < nstH) {
                #pragma unroll
                for (int jt = 0; jt < 4; ++jt) {
                    int j = jb + jt * 16 + lr;
                    #pragma unroll
                    for (int i = 0; i < 4; ++i) {
                        int s = st * 16 + lo8 * 4 + i;
                        short h, l; splitf(acc1[st][jt][i], h, l);
                        int o = qoff(s, j);
                        qh[o] = h; ql[o] = l;
                    }
                }
            }
        }
        __syncthreads();

        // ---- Phase 2 (MFMA): att = q @ hist^T, fold masked max over s ----
        if (nht > 0) {
            f32x4 acc2[2][4];
            #pragma unroll
            for (int st = 0; st < 2; ++st)
                #pragma unroll
                for (int ht = 0; ht < 4; ++ht) acc2[st][ht] = f32x4{0.f, 0.f, 0.f, 0.f};

            float4 pr[2][2];   // prefetched raw hist for ht 0,1
            #pragma unroll
            for (int hp = 0; hp < 2; ++hp) if (hp < nht) {
                const float* p = hrow + (size_t)(hb + hp * 16 + lr) * 256 + lo8 * 8;
                pr[hp][0] = *(const float4*)p; pr[hp][1] = *(const float4*)(p + 4);
            }
            for (int kc = 0; kc < 8; ++kc) {
                float4 cr[2][2];   // ht 2,3 raw, loaded this iteration
                #pragma unroll
                for (int hp = 0; hp < 2; ++hp) if (hp + 2 < nht) {
                    const float* p = hrow + (size_t)(hb + (hp + 2) * 16 + lr) * 256 + kc * 32 + lo8 * 8;
                    cr[hp][0] = *(const float4*)p; cr[hp][1] = *(const float4*)(p + 4);
                }
                bf16x8 a2h[2], a2l[2];
                #pragma unroll
                for (int st = 0; st < 2; ++st) if (st < nstH) {
                    int o = qoff(st * 16 + lr, kc * 32 + lo8 * 8);
                    a2h[st] = *(const bf16x8*)&qh[o];
                    a2l[st] = *(const bf16x8*)&ql[o];
                }
                bf16x8 b0h, b0l, b1h, b1l;
                if (0 < nht) cvt8r(pr[0][0], pr[0][1], b0h, b0l);
                if (1 < nht) cvt8r(pr[1][0], pr[1][1], b1h, b1l);
                if (kc < 7) {   // prefetch ht 0,1 for next kc
                    #pragma unroll
                    for (int hp = 0; hp < 2; ++hp) if (hp < nht) {
                        const float* p = hrow + (size_t)(hb + hp * 16 + lr) * 256 + (kc + 1) * 32 + lo8 * 8;
                        pr[hp][0] = *(const float4*)p; pr[hp][1] = *(const float4*)(p + 4);
                    }
                }
                if (0 < nht) {
                    acc2[0][0] = mac3(a2h[0], a2l[0], b0h, b0l, acc2[0][0]);
                    if (nstH > 1) acc2[1][0] = mac3(a2h[1], a2l[1], b0h, b0l, acc2[1][0]);
                }
                if (1 < nht) {
                    acc2[0][1] = mac3(a2h[0], a2l[0], b1h, b1l, acc2[0][1]);
                    if (nstH > 1) acc2[1][1] = mac3(a2h[1], a2l[1], b1h, b1l, acc2[1][1]);
                }
                #pragma unroll
                for (int hp = 0; hp < 2; ++hp) if (hp + 2 < nht) {
                    bf16x8 bh, bl; cvt8r(cr[hp][0], cr[hp][1], bh, bl);
                    acc2[0][hp + 2] = mac3(a2h[0], a2l[0], bh, bl, acc2[0][hp + 2]);
                    if (nstH > 1) acc2[1][hp + 2] = mac3(a2h[1], a2l[1], bh, bl, acc2[1][hp + 2]);
                }
            }
            #pragma unroll
            for (int ht = 0; ht < 4; ++ht) if (ht < nht) {
                #pragma unroll
                for (int st = 0; st < 2; ++st) if (st < nstH) {
                    #pragma unroll
                    for (int i = 0; i < 4; ++i) {
                        int s = s0 + st * 16 + lo8 * 4 + i;
                        if (s < sl) mrun[ht] = fmaxf(mrun[ht], acc2[st][ht][i]);
                    }
                }
            }
        }
        __syncthreads();
    }

    // ---- finalize per-h score ----
    if (nsh > 0 && nht > 0) {
        #pragma unroll
        for (int ht = 0; ht < 4; ++ht) if (ht < nht) {
            float m = mrun[ht];
            m = fmaxf(m, __shfl_xor(m, 16, 64));
            m = fmaxf(m, __shfl_xor(m, 32, 64));
            int h = hb + ht * 16 + lr;
            if (lane < 16 && h < hl) sMax[h] = m;
        }
    }
    __syncthreads();

    // ---- Phase 3: score out + exact softmax over h (wave shuffles) ----
    float sc = sMax[t];
    out[(size_t)NB * 256 + (size_t)b * 256 + t] = sc;
    float m = sc;
    #pragma unroll
    for (int off = 1; off < 64; off <<= 1) m = fmaxf(m, __shfl_xor(m, off, 64));
    if (lane == 0) red[wave] = m;
    __syncthreads();
    m = fmaxf(fmaxf(red[0], red[1]), fmaxf(red[2], red[3]));
    float e = expf(sc - m);   // all-NULL case: exp(0)=1 -> uniform weights
    float ss = e;
    #pragma unroll
    for (int off = 1; off < 64; off <<= 1) ss += __shfl_xor(ss, off, 64);
    if (lane == 0) red[4 + wave] = ss;
    __syncthreads();
    const float ssum = red[4] + red[5] + red[6] + red[7];
    wts[t] = e / ssum;
    __syncthreads();

    // ---- Phase 4: weighted history sum, column j=t (coalesced, 8-deep) ----
    const int hcount = (m == NULL_ATT) ? 256 : hl;  // exp(NULL-m)==0 exactly otherwise
    const float* hcol = user_hist + (size_t)b * 256 * 256 + t;
    float r[8] = {0.f, 0.f, 0.f, 0.f, 0.f, 0.f, 0.f, 0.f};
    int h = 0;
    for (; h + 8 <= hcount; h += 8) {
        #pragma unroll
        for (int u = 0; u < 8; ++u)
            r[u] += wts[h + u] * hcol[(size_t)(h + u) * 256];
    }
    for (; h < hcount; ++h) r[0] += wts[h] * hcol[(size_t)h * 256];
    out[(size_t)b * 256 + t] = ((r[0] + r[1]) + (r[2] + r[3])) + ((r[4] + r[5]) + (r[6] + r[7]));
}

extern "C" void kernel_launch(void* const* d_in, const int* in_sizes, int n_in,
                              void* d_out, int out_size, void* d_ws, size_t ws_size,
                              hipStream_t stream) {
    const float* item_emb    = (const float*)d_in[0];
    const float* x_session   = (const float*)d_in[1];
    const int*   session_len = (const int*)d_in[2];
    const float* user_hist   = (const float*)d_in[3];
    const int*   hist_len    = (const int*)d_in[4];
    const float* W1          = (const float*)d_in[5];
    const float* b1          = (const float*)d_in[6];
    float* out = (float*)d_out;

    split_w1<<<256, 256, 0, stream>>>(W1);
    calc_iq<<<NB, 256, 0, stream>>>(item_emb, W1, b1);
    coatt_fused<<<NB, 256, 0, stream>>>(x_session, session_len, user_hist, hist_len, out);
}

// Round 4
// 240.987 us; speedup vs baseline: 2.0012x; 2.0012x over previous
//
#include <hip/hip_runtime.h>

#define NB 2048
#define NULL_ATT (-4194304.0f)

typedef __attribute__((ext_vector_type(8))) _Float16 f16x8;
typedef __attribute__((ext_vector_type(4))) float f32x4;

// Precomputed once per launch (module-scope device memory; no hipMalloc).
__device__ __align__(16) short g_wxf16[256 * 256];  // f16 of W1[:,256:512], [j][k]
__device__ float g_iq[NB * 256];                    // item@W1i^T + b1

// swizzled element offset into a [64][256] f16 LDS array (16B granules,
// XOR by (s&7): A-frag reads become 2-way bank aliasing = free).
__device__ __forceinline__ int qoff(int s, int k) {
    int g = k >> 3;
    return s * 256 + (((g ^ (s & 7)) << 3) | (k & 7));
}

__device__ __forceinline__ f16x8 cvt8h(float4 a, float4 b) {
    f16x8 r;
    r[0] = (_Float16)a.x; r[1] = (_Float16)a.y; r[2] = (_Float16)a.z; r[3] = (_Float16)a.w;
    r[4] = (_Float16)b.x; r[5] = (_Float16)b.y; r[6] = (_Float16)b.z; r[7] = (_Float16)b.w;
    return r;
}

__global__ void conv_w1(const float* __restrict__ W1) {
    int j = blockIdx.x, k = threadIdx.x;
    g_wxf16[j * 256 + k] = __builtin_bit_cast(short, (_Float16)W1[(size_t)j * 512 + 256 + k]);
}

// iq[m][j] = item[m,:] @ W1[j, :256] + b1[j]   (M=2048, N=256, K=256, f16 MFMA)
__global__ __launch_bounds__(256, 4) void iq_gemm(const float* __restrict__ item_emb,
                                                  const float* __restrict__ W1,
                                                  const float* __restrict__ b1) {
    const int m0 = blockIdx.x * 64;
    const int t = threadIdx.x, wave = t >> 6, lane = t & 63;
    const int lr = lane & 15, lo8 = lane >> 4;
    const int jb = wave * 64;
    f32x4 acc[4][4];
    #pragma unroll
    for (int mt = 0; mt < 4; ++mt)
        #pragma unroll
        for (int jt = 0; jt < 4; ++jt) acc[mt][jt] = f32x4{0.f, 0.f, 0.f, 0.f};
    #pragma unroll
    for (int kc = 0; kc < 8; ++kc) {
        f16x8 afr[4];
        #pragma unroll
        for (int mt = 0; mt < 4; ++mt) {
            const float* p = item_emb + (size_t)(m0 + mt * 16 + lr) * 256 + kc * 32 + lo8 * 8;
            afr[mt] = cvt8h(*(const float4*)p, *(const float4*)(p + 4));
        }
        #pragma unroll
        for (int jt = 0; jt < 4; ++jt) {
            const float* wp = W1 + (size_t)(jb + jt * 16 + lr) * 512 + kc * 32 + lo8 * 8;
            f16x8 bfr = cvt8h(*(const float4*)wp, *(const float4*)(wp + 4));
            #pragma unroll
            for (int mt = 0; mt < 4; ++mt)
                acc[mt][jt] = __builtin_amdgcn_mfma_f32_16x16x32_f16(afr[mt], bfr, acc[mt][jt], 0, 0, 0);
        }
    }
    #pragma unroll
    for (int jt = 0; jt < 4; ++jt) {
        float bv = b1[jb + jt * 16 + lr];
        #pragma unroll
        for (int mt = 0; mt < 4; ++mt)
            #pragma unroll
            for (int i = 0; i < 4; ++i)
                g_iq[(size_t)(m0 + mt * 16 + lo8 * 4 + i) * 256 + jb + jt * 16 + lr] =
                    acc[mt][jt][i] + bv;
    }
}

__global__ __launch_bounds__(256, 4) void coatt_main(
    const float* __restrict__ x_session,   // [B,64,256]
    const int*   __restrict__ session_len, // [B]
    const float* __restrict__ user_hist,   // [B,256,256]
    const int*   __restrict__ hist_len,    // [B]
    float* __restrict__ out)               // [B*256 rep | B*256 score]
{
    const int b = blockIdx.x;
    const int t = threadIdx.x;
    const int wave = t >> 6;
    const int lane = t & 63;
    const int lr  = lane & 15;
    const int lo8 = lane >> 4;
    const int sl = session_len[b];
    const int hl = hist_len[b];

    __shared__ __align__(16) short qf[64 * 256];   // 32 KB f16 query tile
    __shared__ float sMax[256];
    __shared__ float wts[256];
    __shared__ float red[8];

    sMax[t] = NULL_ATT;
    const int nst = (sl > 0) ? min(4, (sl + 15) >> 4) : 0;

    // ---- Phase 1 (f16 MFMA): q[s][j] = iq[j] + x[s,:] @ W1x[j,:]  ----
    if (nst > 0) {
        const int jb = wave * 64;
        float iqv[4];
        #pragma unroll
        for (int jt = 0; jt < 4; ++jt) iqv[jt] = g_iq[(size_t)b * 256 + jb + jt * 16 + lr];
        const float* xB = x_session + (size_t)b * 64 * 256;
        for (int st = 0; st < nst; ++st) {
            // stage this lane's whole x-row slice set (16 loads in flight)
            const float* xp = xB + (size_t)(st * 16 + lr) * 256 + lo8 * 8;
            float4 xr[8][2];
            #pragma unroll
            for (int kc = 0; kc < 8; ++kc) {
                xr[kc][0] = *(const float4*)(xp + kc * 32);
                xr[kc][1] = *(const float4*)(xp + kc * 32 + 4);
            }
            f32x4 acc[4];
            #pragma unroll
            for (int jt = 0; jt < 4; ++jt) acc[jt] = f32x4{iqv[jt], iqv[jt], iqv[jt], iqv[jt]};
            #pragma unroll
            for (int kc = 0; kc < 8; ++kc) {
                f16x8 a = cvt8h(xr[kc][0], xr[kc][1]);
                #pragma unroll
                for (int jt = 0; jt < 4; ++jt) {
                    f16x8 bfr = *(const f16x8*)&g_wxf16[(jb + jt * 16 + lr) * 256 + kc * 32 + lo8 * 8];
                    acc[jt] = __builtin_amdgcn_mfma_f32_16x16x32_f16(a, bfr, acc[jt], 0, 0, 0);
                }
            }
            #pragma unroll
            for (int jt = 0; jt < 4; ++jt) {
                int j = jb + jt * 16 + lr;
                #pragma unroll
                for (int i = 0; i < 4; ++i) {
                    int s = st * 16 + lo8 * 4 + i;
                    qf[qoff(s, j)] = __builtin_bit_cast(short, (_Float16)acc[jt][i]);
                }
            }
        }
    }
    __syncthreads();

    // ---- Phase 2 (f16 MFMA): att = q @ hist^T, masked max -> sMax ----
    if (nst > 0 && hl > 0) {
        const int nht = (hl + 15) >> 4;               // total active h-tiles (1..16)
        const float* hB = user_hist + (size_t)b * 256 * 256;
        for (int slot = 0; slot < 4; ++slot) {
            const int ht = wave + slot * 4;            // round-robin across waves
            if (ht >= nht) break;
            // stage this lane's whole hist-row slice set (16 loads in flight)
            const float* hp = hB + (size_t)(ht * 16 + lr) * 256 + lo8 * 8;
            float4 hr[8][2];
            #pragma unroll
            for (int kc = 0; kc < 8; ++kc) {
                hr[kc][0] = *(const float4*)(hp + kc * 32);
                hr[kc][1] = *(const float4*)(hp + kc * 32 + 4);
            }
            f32x4 acc[4];
            #pragma unroll
            for (int st = 0; st < 4; ++st) acc[st] = f32x4{0.f, 0.f, 0.f, 0.f};
            #pragma unroll
            for (int kc = 0; kc < 8; ++kc) {
                f16x8 bfr = cvt8h(hr[kc][0], hr[kc][1]);
                #pragma unroll
                for (int st = 0; st < 4; ++st) {
                    if (st < nst) {
                        f16x8 a = *(const f16x8*)&qf[qoff(st * 16 + lr, kc * 32 + lo8 * 8)];
                        acc[st] = __builtin_amdgcn_mfma_f32_16x16x32_f16(a, bfr, acc[st], 0, 0, 0);
                    }
                }
            }
            float m = NULL_ATT;
            #pragma unroll
            for (int st = 0; st < 4; ++st) {
                if (st < nst) {
                    #pragma unroll
                    for (int i = 0; i < 4; ++i) {
                        int s = st * 16 + lo8 * 4 + i;
                        if (s < sl) m = fmaxf(m, acc[st][i]);
                    }
                }
            }
            m = fmaxf(m, __shfl_xor(m, 16, 64));
            m = fmaxf(m, __shfl_xor(m, 32, 64));
            int h = ht * 16 + lr;
            if (lane < 16 && h < hl) sMax[h] = m;
        }
    }
    __syncthreads();

    // ---- Phase 3: score out + exact softmax over h (wave shuffles) ----
    float sc = sMax[t];
    out[(size_t)NB * 256 + (size_t)b * 256 + t] = sc;
    float m = sc;
    #pragma unroll
    for (int off = 1; off < 64; off <<= 1) m = fmaxf(m, __shfl_xor(m, off, 64));
    if (lane == 0) red[wave] = m;
    __syncthreads();
    m = fmaxf(fmaxf(red[0], red[1]), fmaxf(red[2], red[3]));
    float e = expf(sc - m);   // all-NULL case: exp(0)=1 -> uniform weights
    float ss = e;
    #pragma unroll
    for (int off = 1; off < 64; off <<= 1) ss += __shfl_xor(ss, off, 64);
    if (lane == 0) red[4 + wave] = ss;
    __syncthreads();
    const float ssum = red[4] + red[5] + red[6] + red[7];
    wts[t] = e / ssum;
    __syncthreads();

    // ---- Phase 4: weighted history sum, column j=t (coalesced, 8-deep) ----
    const int hcount = (m == NULL_ATT) ? 256 : hl;  // exp(NULL-m)==0 exactly otherwise
    const float* hcol = user_hist + (size_t)b * 256 * 256 + t;
    float r[8] = {0.f, 0.f, 0.f, 0.f, 0.f, 0.f, 0.f, 0.f};
    int h = 0;
    for (; h + 8 <= hcount; h += 8) {
        #pragma unroll
        for (int u = 0; u < 8; ++u)
            r[u] += wts[h + u] * hcol[(size_t)(h + u) * 256];
    }
    for (; h < hcount; ++h) r[0] += wts[h] * hcol[(size_t)h * 256];
    out[(size_t)b * 256 + t] = ((r[0] + r[1]) + (r[2] + r[3])) + ((r[4] + r[5]) + (r[6] + r[7]));
}

extern "C" void kernel_launch(void* const* d_in, const int* in_sizes, int n_in,
                              void* d_out, int out_size, void* d_ws, size_t ws_size,
                              hipStream_t stream) {
    const float* item_emb    = (const float*)d_in[0];
    const float* x_session   = (const float*)d_in[1];
    const int*   session_len = (const int*)d_in[2];
    const float* user_hist   = (const float*)d_in[3];
    const int*   hist_len    = (const int*)d_in[4];
    const float* W1          = (const float*)d_in[5];
    const float* b1          = (const float*)d_in[6];
    float* out = (float*)d_out;

    conv_w1<<<256, 256, 0, stream>>>(W1);
    iq_gemm<<<32, 256, 0, stream>>>(item_emb, W1, b1);
    coatt_main<<<NB, 256, 0, stream>>>(x_session, session_len, user_hist, hist_len, out);
}

// Round 5
// 214.651 us; speedup vs baseline: 2.2468x; 1.1227x over previous
//
#include <hip/hip_runtime.h>

#define NB 2048
#define NULL_ATT (-4194304.0f)

typedef __attribute__((ext_vector_type(8))) _Float16 f16x8;
typedef __attribute__((ext_vector_type(4))) float f32x4;

// Precomputed once per launch (module-scope device memory; no hipMalloc).
__device__ __align__(16) short g_wxf16[256 * 256];  // f16 of W1[:,256:512], [j][k]
__device__ float g_iq[NB * 256];                    // item@W1i^T + b1

// swizzled element offset into a [64][256] f16 LDS array (16B granules,
// XOR by (s&7): phase-2 A-frag ds_read_b128 is 2-way aliasing = free).
__device__ __forceinline__ int qoff(int s, int k) {
    int g = k >> 3;
    return s * 256 + (((g ^ (s & 7)) << 3) | (k & 7));
}

__device__ __forceinline__ f16x8 cvt8h(float4 a, float4 b) {
    f16x8 r;
    r[0] = (_Float16)a.x; r[1] = (_Float16)a.y; r[2] = (_Float16)a.z; r[3] = (_Float16)a.w;
    r[4] = (_Float16)b.x; r[5] = (_Float16)b.y; r[6] = (_Float16)b.z; r[7] = (_Float16)b.w;
    return r;
}

__global__ void conv_w1(const float* __restrict__ W1) {
    int j = blockIdx.x, k = threadIdx.x;
    g_wxf16[j * 256 + k] = __builtin_bit_cast(short, (_Float16)W1[(size_t)j * 512 + 256 + k]);
}

// iq[m][j] = item[m,:] @ W1[j,:256] + b1[j]   (M=2048 in 16-row tiles)
__global__ __launch_bounds__(256, 4) void iq_gemm(const float* __restrict__ item_emb,
                                                  const float* __restrict__ W1,
                                                  const float* __restrict__ b1) {
    const int m0 = blockIdx.x * 16;
    const int t = threadIdx.x, wave = t >> 6, lane = t & 63;
    const int lr = lane & 15, lo8 = lane >> 4;
    const int jb = wave * 64;

    const float* ip = item_emb + (size_t)(m0 + lr) * 256 + lo8 * 8;
    float4 ir[8][2];
    #pragma unroll
    for (int kc = 0; kc < 8; ++kc) {
        ir[kc][0] = *(const float4*)(ip + kc * 32);
        ir[kc][1] = *(const float4*)(ip + kc * 32 + 4);
    }
    f16x8 afr[8];
    #pragma unroll
    for (int kc = 0; kc < 8; ++kc) afr[kc] = cvt8h(ir[kc][0], ir[kc][1]);

    f32x4 acc[4];
    #pragma unroll
    for (int jt = 0; jt < 4; ++jt) acc[jt] = f32x4{0.f, 0.f, 0.f, 0.f};
    #pragma unroll
    for (int kc = 0; kc < 8; ++kc) {
        #pragma unroll
        for (int jt = 0; jt < 4; ++jt) {
            const float* wp = W1 + (size_t)(jb + jt * 16 + lr) * 512 + kc * 32 + lo8 * 8;
            f16x8 bfr = cvt8h(*(const float4*)wp, *(const float4*)(wp + 4));
            acc[jt] = __builtin_amdgcn_mfma_f32_16x16x32_f16(afr[kc], bfr, acc[jt], 0, 0, 0);
        }
    }
    #pragma unroll
    for (int jt = 0; jt < 4; ++jt) {
        float bv = b1[jb + jt * 16 + lr];
        #pragma unroll
        for (int i = 0; i < 4; ++i)
            g_iq[(size_t)(m0 + lo8 * 4 + i) * 256 + jb + jt * 16 + lr] = acc[jt][i] + bv;
    }
}

__global__ __launch_bounds__(256, 4) void coatt_main(
    const float* __restrict__ x_session,   // [B,64,256]
    const int*   __restrict__ session_len, // [B]
    const float* __restrict__ user_hist,   // [B,256,256]
    const int*   __restrict__ hist_len,    // [B]
    float* __restrict__ out)               // [B*256 rep | B*256 score]
{
    const int b = blockIdx.x;
    const int t = threadIdx.x;
    const int wave = t >> 6;
    const int lane = t & 63;
    const int lr  = lane & 15;
    const int lo8 = lane >> 4;
    const int sl = session_len[b];
    const int hl = hist_len[b];

    __shared__ __align__(16) short qf[64 * 256];   // 32 KB f16 query tile
    __shared__ float sMax[256];
    __shared__ float wts[256];
    __shared__ float red[8];
    __shared__ __align__(16) float pw[4][256];     // phase-4 partials

    sMax[t] = NULL_ATT;
    const int nst = (sl > 0) ? min(4, (sl + 15) >> 4) : 0;

    // ---- Phase 1 (f16 MFMA): wave w owns s-tile w ----
    if (wave < nst) {
        const int st = wave;
        const float* xp = x_session + ((size_t)b * 64 + st * 16 + lr) * 256 + lo8 * 8;
        float4 xr[8][2];
        #pragma unroll
        for (int kc = 0; kc < 8; ++kc) {
            xr[kc][0] = *(const float4*)(xp + kc * 32);
            xr[kc][1] = *(const float4*)(xp + kc * 32 + 4);
        }
        f16x8 afr[8];
        #pragma unroll
        for (int kc = 0; kc < 8; ++kc) afr[kc] = cvt8h(xr[kc][0], xr[kc][1]);

        #pragma unroll
        for (int jc = 0; jc < 4; ++jc) {
            f32x4 acc[4];
            #pragma unroll
            for (int jt = 0; jt < 4; ++jt) {
                float v = g_iq[(size_t)b * 256 + jc * 64 + jt * 16 + lr];
                acc[jt] = f32x4{v, v, v, v};
            }
            #pragma unroll
            for (int kc = 0; kc < 8; ++kc) {
                #pragma unroll
                for (int jt = 0; jt < 4; ++jt) {
                    f16x8 bfr = *(const f16x8*)&g_wxf16[(jc * 64 + jt * 16 + lr) * 256 + kc * 32 + lo8 * 8];
                    acc[jt] = __builtin_amdgcn_mfma_f32_16x16x32_f16(afr[kc], bfr, acc[jt], 0, 0, 0);
                }
            }
            #pragma unroll
            for (int jt = 0; jt < 4; ++jt) {
                int j = jc * 64 + jt * 16 + lr;
                #pragma unroll
                for (int i = 0; i < 4; ++i)
                    qf[qoff(st * 16 + lo8 * 4 + i, j)] =
                        __builtin_bit_cast(short, (_Float16)acc[jt][i]);
            }
        }
    }

    // ---- hoist slot-0 hist loads above the barrier (independent of q) ----
    const int nht = (hl + 15) >> 4;
    const bool p2 = (nst > 0 && hl > 0);
    const float* hB = user_hist + (size_t)b * 256 * 256;
    float4 hr[8][2];
    if (p2 && wave < nht) {
        const float* hp = hB + (size_t)(wave * 16 + lr) * 256 + lo8 * 8;
        #pragma unroll
        for (int kc = 0; kc < 8; ++kc) {
            hr[kc][0] = *(const float4*)(hp + kc * 32);
            hr[kc][1] = *(const float4*)(hp + kc * 32 + 4);
        }
    }
    __syncthreads();

    // ---- Phase 2 (f16 MFMA): att = q @ hist^T, masked max; cross-slot prefetch ----
    if (p2) {
        for (int slot = 0; slot < 4; ++slot) {
            const int ht = wave + slot * 4;
            if (ht >= nht) break;
            const int htn = ht + 4;
            const bool pre = (htn < nht);
            const float* hpn = hB + (size_t)(htn * 16 + lr) * 256 + lo8 * 8;
            f32x4 acc[4];
            #pragma unroll
            for (int st = 0; st < 4; ++st) acc[st] = f32x4{0.f, 0.f, 0.f, 0.f};
            #pragma unroll
            for (int kc = 0; kc < 8; ++kc) {
                f16x8 bfr = cvt8h(hr[kc][0], hr[kc][1]);
                if (pre) {   // reuse regs: issue next slot's loads (WAR-safe)
                    hr[kc][0] = *(const float4*)(hpn + kc * 32);
                    hr[kc][1] = *(const float4*)(hpn + kc * 32 + 4);
                }
                #pragma unroll
                for (int st = 0; st < 4; ++st) {
                    if (st < nst) {
                        f16x8 a = *(const f16x8*)&qf[qoff(st * 16 + lr, kc * 32 + lo8 * 8)];
                        acc[st] = __builtin_amdgcn_mfma_f32_16x16x32_f16(a, bfr, acc[st], 0, 0, 0);
                    }
                }
            }
            float m = NULL_ATT;
            #pragma unroll
            for (int st = 0; st < 4; ++st) {
                if (st < nst) {
                    #pragma unroll
                    for (int i = 0; i < 4; ++i) {
                        int s = st * 16 + lo8 * 4 + i;
                        if (s < sl) m = fmaxf(m, acc[st][i]);
                    }
                }
            }
            m = fmaxf(m, __shfl_xor(m, 16, 64));
            m = fmaxf(m, __shfl_xor(m, 32, 64));
            int h = ht * 16 + lr;
            if (lane < 16 && h < hl) sMax[h] = m;
        }
    }
    __syncthreads();

    // ---- Phase 3: score out + exact softmax over h (wave shuffles) ----
    float sc = sMax[t];
    out[(size_t)NB * 256 + (size_t)b * 256 + t] = sc;
    float m = sc;
    #pragma unroll
    for (int off = 1; off < 64; off <<= 1) m = fmaxf(m, __shfl_xor(m, off, 64));
    if (lane == 0) red[wave] = m;
    __syncthreads();
    m = fmaxf(fmaxf(red[0], red[1]), fmaxf(red[2], red[3]));
    float e = expf(sc - m);   // all-NULL case: exp(0)=1 -> uniform weights
    float ss = e;
    #pragma unroll
    for (int off = 1; off < 64; off <<= 1) ss += __shfl_xor(ss, off, 64);
    if (lane == 0) red[4 + wave] = ss;
    __syncthreads();
    const float ssum = red[4] + red[5] + red[6] + red[7];
    wts[t] = e / ssum;
    __syncthreads();

    // ---- Phase 4: weighted hist sum; wave w takes h = w (mod 4), float4 lanes ----
    const int hcount = (m == NULL_ATT) ? 256 : hl;  // exp(NULL-m)==0 exactly otherwise
    f32x4 a4 = {0.f, 0.f, 0.f, 0.f};
    {
        const float* hc = hB + lane * 4;
        int h = wave;
        for (; h + 12 < hcount; h += 16) {
            float4 v0 = *(const float4*)(hc + (size_t)(h)      * 256);
            float4 v1 = *(const float4*)(hc + (size_t)(h + 4)  * 256);
            float4 v2 = *(const float4*)(hc + (size_t)(h + 8)  * 256);
            float4 v3 = *(const float4*)(hc + (size_t)(h + 12) * 256);
            float w0 = wts[h], w1 = wts[h + 4], w2 = wts[h + 8], w3 = wts[h + 12];
            a4[0] += w0 * v0.x + w1 * v1.x + w2 * v2.x + w3 * v3.x;
            a4[1] += w0 * v0.y + w1 * v1.y + w2 * v2.y + w3 * v3.y;
            a4[2] += w0 * v0.z + w1 * v1.z + w2 * v2.z + w3 * v3.z;
            a4[3] += w0 * v0.w + w1 * v1.w + w2 * v2.w + w3 * v3.w;
        }
        for (; h < hcount; h += 4) {
            float4 v = *(const float4*)(hc + (size_t)h * 256);
            float w0 = wts[h];
            a4[0] += w0 * v.x; a4[1] += w0 * v.y; a4[2] += w0 * v.z; a4[3] += w0 * v.w;
        }
    }
    *(float4*)&pw[wave][lane * 4] = *(float4*)&a4;
    __syncthreads();
    out[(size_t)b * 256 + t] = (pw[0][t] + pw[1][t]) + (pw[2][t] + pw[3][t]);
}

extern "C" void kernel_launch(void* const* d_in, const int* in_sizes, int n_in,
                              void* d_out, int out_size, void* d_ws, size_t ws_size,
                              hipStream_t stream) {
    const float* item_emb    = (const float*)d_in[0];
    const float* x_session   = (const float*)d_in[1];
    const int*   session_len = (const int*)d_in[2];
    const float* user_hist   = (const float*)d_in[3];
    const int*   hist_len    = (const int*)d_in[4];
    const float* W1          = (const float*)d_in[5];
    const float* b1          = (const float*)d_in[6];
    float* out = (float*)d_out;

    conv_w1<<<256, 256, 0, stream>>>(W1);
    iq_gemm<<<128, 256, 0, stream>>>(item_emb, W1, b1);
    coatt_main<<<NB, 256, 0, stream>>>(x_session, session_len, user_hist, hist_len, out);
}